// Round 7
// baseline (898.498 us; speedup 1.0000x reference)
//
#include <hip/hip_runtime.h>
#include <math.h>
#include <limits.h>

#define N_NODES  50000
#define N_EDGES  1000000
#define INV_AVG  0.05f   // N_NODES / N_EDGES
#define DSENT    INT_MAX
#define TSIZE    8192
#define TMAX     1.7400f

// ---------------- compile-time path tables ----------------
constexpr int PL1[15] = {0,0,0,1,1,1,1,1,1,2,2,2,2,2,2};
constexpr int PL2[15] = {0,1,2,0,1,1,1,2,2,0,1,1,2,2,2};
constexpr int PCGOFF[16] = {0,1,10,35,44,53,80,125,170,245,270,315,390,415,490,615};
constexpr float PALPHA[15] = {
    0.20412414523193154f, 0.14433756729740643f, 0.14433756729740643f,
    0.14433756729740643f, 0.20412414523193154f, 0.14433756729740643f,
    0.14433756729740643f, 0.14433756729740643f, 0.14433756729740643f,
    0.14433756729740643f, 0.14433756729740643f, 0.14433756729740643f,
    0.20412414523193154f, 0.14433756729740643f, 0.14433756729740643f};

// runtime copies for cg_init
__device__ __constant__ int c_L1[15]   = {0,0,0,1,1,1,1,1,1,2,2,2,2,2,2};
__device__ __constant__ int c_L2[15]   = {0,1,2,0,1,1,1,2,2,0,1,1,2,2,2};
__device__ __constant__ int c_L3[15]   = {0,1,2,1,0,1,2,1,2,2,1,2,0,1,2};
__device__ __constant__ int c_CGOFF[16] = {0,1,10,35,44,53,80,125,170,245,270,315,390,415,490,615};

// ---------------- CG math (verified r1) ----------------
struct cplxd { double re, im; };

__device__ inline double factd(int n) {
    double r = 1.0;
    for (int i = 2; i <= n; ++i) r *= (double)i;
    return r;
}

__device__ double cgc(int j1, int j2, int j3, int m1, int m2, int m3) {
    if (m1 + m2 != m3) return 0.0;
    double pre = sqrt((double)(2*j3+1) * factd(j3+j1-j2) * factd(j3-j1+j2) *
                      factd(j1+j2-j3) / factd(j1+j2+j3+1));
    pre *= sqrt(factd(j3+m3)*factd(j3-m3)*factd(j1-m1)*factd(j1+m1)*
                factd(j2-m2)*factd(j2+m2));
    double s = 0.0;
    for (int k = 0; k <= j1+j2-j3; ++k) {
        int d1 = j1+j2-j3-k, d2 = j1-m1-k, d3 = j2+m2-k,
            d4 = j3-j2+m1+k, d5 = j3-j1-m2+k;
        if (d1 < 0 || d2 < 0 || d3 < 0 || d4 < 0 || d5 < 0) continue;
        double term = 1.0 / (factd(k)*factd(d1)*factd(d2)*factd(d3)*factd(d4)*factd(d5));
        s += (k & 1) ? -term : term;
    }
    return pre * s;
}

__device__ inline cplxd qent(int l, int a, int i) {
    const double r2 = 0.70710678118654752440;
    double re = 0.0, im = 0.0;
    int m = a - l;
    if (m < 0) {
        if (i == l - m)      re = r2;
        else if (i == l + m) im = -r2;
    } else if (m == 0) {
        if (i == l) re = 1.0;
    } else {
        double s = (m & 1) ? -1.0 : 1.0;
        if (i == l + m)      re = s * r2;
        else if (i == l - m) im = s * r2;
    }
    if (l == 1)      { double t = re; re = im; im = -t; }  // * (-i)
    else if (l == 2) { re = -re; im = -im; }               // * (-1)
    cplxd q; q.re = re; q.im = im; return q;
}

__device__ inline float silu_f(float x) { return x / (1.0f + __expf(-x)); }

// ---------------- merged setup kernel ----------------
// block 0        : CG init
// blocks 1..8    : gate table (alpha AND 1/avg folded in)
// blocks 9..57   : node MLP
// blocks 58..    : dst histogram
__global__ __launch_bounds__(1024) void setup_kernel(
    float* __restrict__ cg_out,
    const float* __restrict__ fw1, const float* __restrict__ fb1,
    const float* __restrict__ fw2, const float* __restrict__ fb2,
    const float* __restrict__ fw3, const float* __restrict__ fb3,
    float* __restrict__ gtab,
    const int* __restrict__ A, const float* __restrict__ emb_table,
    const float* __restrict__ mw1, const float* __restrict__ mb1,
    const float* __restrict__ mw2, const float* __restrict__ mb2,
    float* __restrict__ Ai,
    const int* __restrict__ edst, int* __restrict__ cnt)
{
    const int blk = blockIdx.x;
    const int t = threadIdx.x;

    if (blk == 0) {
        __shared__ double s_re[615], s_im[615];
        __shared__ int s_flag[15];
        int p = 0;
        if (t < 615) {
            p = 14;
            while (t < c_CGOFF[p]) --p;
            int l1 = c_L1[p], l2 = c_L2[p], l3 = c_L3[p];
            int d1 = 2*l1+1, d2 = 2*l2+1, d3 = 2*l3+1;
            int local = t - c_CGOFF[p];
            int i = local / (d2*d3);
            int r = local - i*d2*d3;
            int j = r / d3;
            int k = r - j*d3;
            double accre = 0.0, accim = 0.0;
            for (int a = 0; a < d1; ++a) {
                cplxd q1 = qent(l1, a, i);
                if (q1.re == 0.0 && q1.im == 0.0) continue;
                for (int b = 0; b < d2; ++b) {
                    cplxd q2 = qent(l2, b, j);
                    if (q2.re == 0.0 && q2.im == 0.0) continue;
                    double t12r = q1.re*q2.re - q1.im*q2.im;
                    double t12i = q1.re*q2.im + q1.im*q2.re;
                    for (int c = 0; c < d3; ++c) {
                        cplxd q3 = qent(l3, c, k);
                        if (q3.re == 0.0 && q3.im == 0.0) continue;
                        int m1 = a-l1, m2 = b-l2, m3 = c-l3;
                        if (m1 + m2 != m3) continue;
                        double C = cgc(l1, l2, l3, m1, m2, m3);
                        if (C == 0.0) continue;
                        double cr = q3.re, ci = -q3.im;  // conj
                        accre += (t12r*cr - t12i*ci) * C;
                        accim += (t12r*ci + t12i*cr) * C;
                    }
                }
            }
            s_re[t] = accre; s_im[t] = accim;
        }
        __syncthreads();
        if (t < 15) {
            double sre = 0.0, sim = 0.0;
            for (int q = c_CGOFF[t]; q < c_CGOFF[t+1]; ++q) {
                sre += fabs(s_re[q]); sim += fabs(s_im[q]);
            }
            s_flag[t] = (sre >= sim) ? 0 : 1;
        }
        __syncthreads();
        if (t < 615) {
            cg_out[t] = (float)(s_flag[p] ? s_im[t] : s_re[t]);
        }
    } else if (blk <= 8) {
        const int idx = (blk - 1) * 1024 + t;
        if (idx >= TSIZE) return;
        const float len = (float)idx * (TMAX / (float)(TSIZE - 1));

        float embv[8];
#pragma unroll
        for (int b = 0; b < 8; ++b) {
            const float ctr = (2.0f/9.0f) * (float)(b+1);
            const float d = (len - ctr) * 4.5f;
            embv[b] = __expf(-d*d) * 2.5253813613805274f;  // sqrt(8)/1.12
        }
        float h1[64];
#pragma unroll
        for (int i = 0; i < 64; ++i) {
            float tt = fb1[i];
#pragma unroll
            for (int b = 0; b < 8; ++b) tt += embv[b] * fw1[b*64 + i];
            h1[i] = silu_f(tt);
        }
        float g[15];
#pragma unroll
        for (int p = 0; p < 15; ++p) g[p] = fb3[p];
        for (int j = 0; j < 64; ++j) {
            float t0 = 0.0f, t1 = 0.0f, t2 = 0.0f, t3 = 0.0f;
#pragma unroll
            for (int i = 0; i < 64; i += 4) {
                t0 += h1[i+0] * fw2[(i+0)*64 + j];
                t1 += h1[i+1] * fw2[(i+1)*64 + j];
                t2 += h1[i+2] * fw2[(i+2)*64 + j];
                t3 += h1[i+3] * fw2[(i+3)*64 + j];
            }
            const float s = silu_f(fb2[j] + ((t0 + t1) + (t2 + t3)));
#pragma unroll
            for (int p = 0; p < 15; ++p) g[p] += s * fw3[j*15 + p];
        }
        float* orow = gtab + (long long)idx * 16;
#pragma unroll
        for (int p = 0; p < 15; ++p) orow[p] = g[p] * PALPHA[p] * INV_AVG;
        orow[15] = 0.0f;
    } else if (blk <= 57) {
        const int v = (blk - 9) * 1024 + t;
        if (v >= N_NODES) return;
        int a = A[v];
        float e[16];
#pragma unroll
        for (int i = 0; i < 16; ++i) e[i] = emb_table[a*16 + i];
        float acc[8];
#pragma unroll
        for (int c = 0; c < 8; ++c) acc[c] = mb2[c];
        for (int j = 0; j < 64; ++j) {
            float tt = mb1[j];
#pragma unroll
            for (int i = 0; i < 16; ++i) tt += e[i] * mw1[i*64 + j];
            tt = silu_f(tt);
#pragma unroll
            for (int c = 0; c < 8; ++c) acc[c] += tt * mw2[j*8 + c];
        }
#pragma unroll
        for (int c = 0; c < 8; ++c) Ai[(long long)v*8 + c] = acc[c];
    } else {
        const long long idx = (long long)(blk - 58) * 1024 + t;
        if (idx < N_EDGES) atomicAdd(&cnt[edst[idx]], 1);
    }
}

// ---------------- scan: exclusive prefix of counts -> cur ----------------
__global__ __launch_bounds__(1024) void scan_kernel(const int* __restrict__ cnt,
                                                    int* __restrict__ cur) {
    __shared__ int sums[1024];
    const int t = threadIdx.x;
    const int per = 49;
    const int base = t * per;
    int s = 0;
    for (int i = 0; i < per; ++i) {
        int idx = base + i;
        if (idx < N_NODES) s += cnt[idx];
    }
    sums[t] = s;
    __syncthreads();
    for (int off = 1; off < 1024; off <<= 1) {
        int v = (t >= off) ? sums[t - off] : 0;
        __syncthreads();
        sums[t] += v;
        __syncthreads();
    }
    int run = (t == 0) ? 0 : sums[t - 1];
    for (int i = 0; i < per; ++i) {
        int idx = base + i;
        if (idx < N_NODES) {
            run += 0;  // keep order: write start, then advance
            cur[idx] = run;
            run += cnt[idx];
        }
    }
}

// ---------------- build: compute geometry + scatter packed sorted records ----------------
__global__ __launch_bounds__(256) void build_kernel(
    const float* __restrict__ pos, const int* __restrict__ batch,
    const int* __restrict__ esrc, const int* __restrict__ edst,
    const float* __restrict__ eshift, const float* __restrict__ cell,
    int* __restrict__ cur,
    unsigned int* __restrict__ epair, float* __restrict__ edata)
{
    long long t = (long long)blockIdx.x * 256 + threadIdx.x;
    if (t >= N_EDGES) return;
    const int src = esrc[t];
    const int d   = edst[t];
    const int p = atomicAdd(&cur[d], 1);

    const int bb = batch[src];
    const float s0 = eshift[3*t+0], s1 = eshift[3*t+1], s2 = eshift[3*t+2];
    const float* cl = cell + (long long)bb * 9;
    const float shx = s0*cl[0] + s1*cl[3] + s2*cl[6];
    const float shy = s0*cl[1] + s1*cl[4] + s2*cl[7];
    const float shz = s0*cl[2] + s1*cl[5] + s2*cl[8];
    const float vx = pos[d*3+0] - pos[src*3+0] + shx;
    const float vy = pos[d*3+1] - pos[src*3+1] + shy;
    const float vz = pos[d*3+2] - pos[src*3+2] + shz;
    const float len = sqrtf(vx*vx + vy*vy + vz*vz);
    const float inv = 1.0f / fmaxf(len, 1e-8f);

    epair[p] = (unsigned int)src | ((unsigned int)d << 16);
    ((float4*)edata)[p] = make_float4(vx*inv, vy*inv, vz*inv, len);
}

// ---------------- per-path TP (all indices compile-time) ----------------
template<int P, int D3>
__device__ __attribute__((always_inline)) inline void process_path(
    float (&acc)[16*D3], const float (&Y)[9], const float (&g)[15],
    const float (&Aiv)[8], const float* __restrict__ cg, const float* __restrict__ tpw)
{
    constexpr int l1 = PL1[P], l2 = PL2[P];
    constexpr int d1 = 2*l1 + 1, d2 = 2*l2 + 1;
    constexpr int cgoff = PCGOFF[P];
    float geo[D3];
#pragma unroll
    for (int k = 0; k < D3; ++k) geo[k] = 0.0f;
#pragma unroll
    for (int m = 0; m < d1; ++m) {
#pragma unroll
        for (int n = 0; n < d2; ++n) {
            float pr = Y[l1*l1 + m] * Y[l2*l2 + n];
#pragma unroll
            for (int k = 0; k < D3; ++k)
                geo[k] += pr * cg[cgoff + (m*d2 + n)*D3 + k];
        }
    }
    float gg[D3];
#pragma unroll
    for (int k = 0; k < D3; ++k) gg[k] = geo[k] * g[P];
    float chan[16];
#pragma unroll
    for (int c = 0; c < 16; ++c) chan[c] = 0.0f;
#pragma unroll
    for (int m = 0; m < 8; ++m) {
#pragma unroll
        for (int c = 0; c < 16; ++c) chan[c] += Aiv[m] * tpw[P*128 + m*16 + c];
    }
#pragma unroll
    for (int c = 0; c < 16; ++c) {
#pragma unroll
        for (int k = 0; k < D3; ++k)
            acc[c*D3 + k] += chan[c] * gg[k];
    }
}

// ---------------- fused edge kernel ----------------
// coalesced packed inputs; TP math; 5× 32-comp staging passes (stride 33,
// 33.8 KB) + segment drains; one coalesced atomic row per segment.
__global__ __launch_bounds__(256, 4) void edge_kernel(
    const unsigned int* __restrict__ epair, const float* __restrict__ edata,
    const float* __restrict__ tpw,  const float* __restrict__ cg,
    const float* __restrict__ Ai,   const float* __restrict__ gtab,
    float* __restrict__ out)
{
    __shared__ float s_stage[256*33];    // 33792 B
    __shared__ int   s_dstsh[256];
    __shared__ int   s_segstart[257];
    __shared__ int   s_segdst[256];
    __shared__ int   s_woff[5];

    const int tid  = threadIdx.x;
    const int wave = tid >> 6, lane = tid & 63;
    const long long e = (long long)blockIdx.x * 256 + tid;
    const bool act = (e < N_EDGES);
    const long long ti = act ? e : 0;

    // ---- coalesced record loads ----
    const unsigned int pk = epair[ti];
    const int src = (int)(pk & 0xffffu);
    const int mydst = act ? (int)(pk >> 16) : DSENT;
    const float4 ed = ((const float4*)edata)[ti];
    const float nx = ed.x, ny = ed.y, nz = ed.z, len = ed.w;

    float Aiv[8];
    {
        const float4* ap = (const float4*)(Ai + (long long)src * 8);
        float4 a0 = ap[0], a1 = ap[1];
        Aiv[0]=a0.x; Aiv[1]=a0.y; Aiv[2]=a0.z; Aiv[3]=a0.w;
        Aiv[4]=a1.x; Aiv[5]=a1.y; Aiv[6]=a1.z; Aiv[7]=a1.w;
    }

    // ---- segment metadata ----
    s_dstsh[tid] = mydst;
    __syncthreads();
    const int prev = (tid == 0) ? (mydst ^ 1) : s_dstsh[tid - 1];
    const int flag = (prev != mydst) ? 1 : 0;
    const unsigned long long mask = __ballot(flag != 0);
    const int excl = __popcll(mask & ((1ull << lane) - 1));
    if (lane == 0) s_woff[wave] = __popcll(mask);
    __syncthreads();
    if (tid == 0) {
        int r = 0;
#pragma unroll
        for (int w = 0; w < 4; ++w) { int c = s_woff[w]; s_woff[w] = r; r += c; }
        s_woff[4] = r;           // nseg
        s_segstart[r] = 256;     // terminator
    }
    __syncthreads();
    const int segid = s_woff[wave] + excl + flag - 1;
    if (flag) { s_segstart[segid] = tid; s_segdst[segid] = mydst; }
    __syncthreads();
    const int nseg = s_woff[4];

    // ---- per-edge math ----
    float Y[9];
    {
        const float s3c = 1.7320508075688772f;
        const float s15 = 3.872983346207417f;
        const float s5 = 2.2360679774997896f;
        Y[0] = 1.0f;
        Y[1] = s3c*ny; Y[2] = s3c*nz; Y[3] = s3c*nx;
        Y[4] = s15*nx*ny; Y[5] = s15*ny*nz;
        Y[6] = 0.5f*s5*(3.0f*nz*nz - 1.0f);
        Y[7] = s15*nx*nz;
        Y[8] = 0.5f*s15*(nx*nx - ny*ny);
    }

    float g[15];
    {
        float f = len * ((float)(TSIZE - 1) / TMAX);
        int i0 = (int)f;
        if (i0 > TSIZE - 2) i0 = TSIZE - 2;
        const float w = f - (float)i0;
        const float* t0 = gtab + (long long)i0 * 16;
        const float* t1 = t0 + 16;
#pragma unroll
        for (int p = 0; p < 15; ++p) g[p] = t0[p] + w * (t1[p] - t0[p]);
    }

    float a0[16], a1[48];
#pragma unroll
    for (int i = 0; i < 16; ++i) a0[i] = 0.0f;
    process_path<0, 1>(a0, Y, g, Aiv, cg, tpw);
    process_path<4, 1>(a0, Y, g, Aiv, cg, tpw);
    process_path<12,1>(a0, Y, g, Aiv, cg, tpw);
#pragma unroll
    for (int i = 0; i < 48; ++i) a1[i] = 0.0f;
    process_path<1, 3>(a1, Y, g, Aiv, cg, tpw);
    process_path<3, 3>(a1, Y, g, Aiv, cg, tpw);
    process_path<5, 3>(a1, Y, g, Aiv, cg, tpw);
    process_path<7, 3>(a1, Y, g, Aiv, cg, tpw);
    process_path<10,3>(a1, Y, g, Aiv, cg, tpw);
    process_path<13,3>(a1, Y, g, Aiv, cg, tpw);

#define DRAIN(BASE, NC, SH, MSK)                                             \
    {                                                                        \
        const int ntask = nseg * (NC);                                       \
        for (int task = tid; task < ntask; task += 256) {                    \
            const int seg = task >> (SH);                                    \
            const int comp = task & (MSK);                                   \
            const int s = s_segstart[seg], epos = s_segstart[seg + 1];       \
            const int d = s_segdst[seg];                                     \
            float sum = 0.0f;                                                \
            int r = s;                                                       \
            for (; r + 4 <= epos; r += 4) {                                  \
                float v0 = s_stage[(r+0)*33 + comp];                         \
                float v1 = s_stage[(r+1)*33 + comp];                         \
                float v2 = s_stage[(r+2)*33 + comp];                         \
                float v3 = s_stage[(r+3)*33 + comp];                         \
                sum += ((v0 + v1) + (v2 + v3));                              \
            }                                                                \
            for (; r < epos; ++r) sum += s_stage[r*33 + comp];               \
            if (d != DSENT)                                                  \
                atomicAdd(&out[(long long)d*144 + (BASE) + comp], sum);      \
        }                                                                    \
    }

    // ---- PASS 0: comps 0..31 = a0[0:16] + a1[0:16] ----
#pragma unroll
    for (int c = 0; c < 32; ++c)
        s_stage[tid*33 + c] = (c < 16) ? a0[c] : a1[c - 16];
    __syncthreads();
    DRAIN(0, 32, 5, 31)
    __syncthreads();

    // ---- PASS 1: comps 32..63 = a1[16:48] ----
#pragma unroll
    for (int c = 0; c < 32; ++c)
        s_stage[tid*33 + c] = a1[16 + c];
    __syncthreads();
    DRAIN(32, 32, 5, 31)
    __syncthreads();

    // chunk2 (a0/a1 dead now)
    float a2[80];
#pragma unroll
    for (int i = 0; i < 80; ++i) a2[i] = 0.0f;
    process_path<2, 5>(a2, Y, g, Aiv, cg, tpw);
    process_path<6, 5>(a2, Y, g, Aiv, cg, tpw);
    process_path<8, 5>(a2, Y, g, Aiv, cg, tpw);
    process_path<9, 5>(a2, Y, g, Aiv, cg, tpw);
    process_path<11,5>(a2, Y, g, Aiv, cg, tpw);
    process_path<14,5>(a2, Y, g, Aiv, cg, tpw);

    // ---- PASS 2: comps 64..95 = a2[0:32] ----
#pragma unroll
    for (int c = 0; c < 32; ++c)
        s_stage[tid*33 + c] = a2[c];
    __syncthreads();
    DRAIN(64, 32, 5, 31)
    __syncthreads();

    // ---- PASS 3: comps 96..127 = a2[32:64] ----
#pragma unroll
    for (int c = 0; c < 32; ++c)
        s_stage[tid*33 + c] = a2[32 + c];
    __syncthreads();
    DRAIN(96, 32, 5, 31)
    __syncthreads();

    // ---- PASS 4: comps 128..143 = a2[64:80] ----
#pragma unroll
    for (int c = 0; c < 16; ++c)
        s_stage[tid*33 + c] = a2[64 + c];
    __syncthreads();
    DRAIN(128, 16, 4, 15)
#undef DRAIN
}

// ---------------- launch ----------------
extern "C" void kernel_launch(void* const* d_in, const int* in_sizes, int n_in,
                              void* d_out, int out_size, void* d_ws, size_t ws_size,
                              hipStream_t stream) {
    const float* pos       = (const float*)d_in[0];
    const int*   A         = (const int*)d_in[1];
    const int*   batch     = (const int*)d_in[2];
    const int*   esrc      = (const int*)d_in[3];
    const int*   edst      = (const int*)d_in[4];
    const float* eshift    = (const float*)d_in[5];
    const float* cell      = (const float*)d_in[6];
    const float* emb_table = (const float*)d_in[7];
    const float* mlp_w1    = (const float*)d_in[8];
    const float* mlp_b1    = (const float*)d_in[9];
    const float* mlp_w2    = (const float*)d_in[10];
    const float* mlp_b2    = (const float*)d_in[11];
    const float* fc_w1     = (const float*)d_in[12];
    const float* fc_b1     = (const float*)d_in[13];
    const float* fc_w2     = (const float*)d_in[14];
    const float* fc_b2     = (const float*)d_in[15];
    const float* fc_w3     = (const float*)d_in[16];
    const float* fc_b3     = (const float*)d_in[17];
    const float* tpw       = (const float*)d_in[18];
    float* out = (float*)d_out;

    // ws layout (float offsets; all 16B-aligned)
    float*        ws_cg    = (float*)d_ws;                  // [0, 1024)
    float*        ws_Ai    = (float*)d_ws + 1024;           // 400000
    float*        ws_gtab  = (float*)d_ws + 401024;         // 131072
    int*          ws_cnt   = (int*)d_ws + 532096;           // 50016
    int*          ws_cur   = (int*)d_ws + 582112;           // 50016
    unsigned int* ws_epair = (unsigned int*)d_ws + 632128;  // 1e6
    float*        ws_edata = (float*)d_ws + 1632128;        // 4e6

    hipMemsetAsync(d_out, 0, (size_t)out_size * sizeof(float), stream);
    hipMemsetAsync(ws_cnt, 0, 50016 * sizeof(int), stream);

    // setup grid: 58 setup blocks + 977 hist blocks
    hipLaunchKernelGGL(setup_kernel, dim3(58 + 977), dim3(1024), 0, stream,
                       ws_cg,
                       fc_w1, fc_b1, fc_w2, fc_b2, fc_w3, fc_b3, ws_gtab,
                       A, emb_table, mlp_w1, mlp_b1, mlp_w2, mlp_b2, ws_Ai,
                       edst, ws_cnt);
    hipLaunchKernelGGL(scan_kernel, dim3(1), dim3(1024), 0, stream, ws_cnt, ws_cur);

    const int eblocks = (N_EDGES + 255) / 256;
    hipLaunchKernelGGL(build_kernel, dim3(eblocks), dim3(256), 0, stream,
                       pos, batch, esrc, edst, eshift, cell,
                       ws_cur, ws_epair, ws_edata);
    hipLaunchKernelGGL(edge_kernel, dim3(eblocks), dim3(256), 0, stream,
                       ws_epair, ws_edata, tpw, ws_cg, ws_Ai, ws_gtab, out);
}

// Round 8
// 736.522 us; speedup vs baseline: 1.2199x; 1.2199x over previous
//
#include <hip/hip_runtime.h>
#include <math.h>
#include <limits.h>

#define N_NODES  50000
#define N_EDGES  1000000
#define INV_AVG  0.05f   // N_NODES / N_EDGES
#define DSENT    INT_MAX
#define TSIZE    8192
#define TMAX     1.7400f

// ---------------- compile-time path tables ----------------
constexpr int PL1[15] = {0,0,0,1,1,1,1,1,1,2,2,2,2,2,2};
constexpr int PL2[15] = {0,1,2,0,1,1,1,2,2,0,1,1,2,2,2};
constexpr int PCGOFF[16] = {0,1,10,35,44,53,80,125,170,245,270,315,390,415,490,615};
constexpr float PALPHA[15] = {
    0.20412414523193154f, 0.14433756729740643f, 0.14433756729740643f,
    0.14433756729740643f, 0.20412414523193154f, 0.14433756729740643f,
    0.14433756729740643f, 0.14433756729740643f, 0.14433756729740643f,
    0.14433756729740643f, 0.14433756729740643f, 0.14433756729740643f,
    0.20412414523193154f, 0.14433756729740643f, 0.14433756729740643f};

// runtime copies for cg_init
__device__ __constant__ int c_L1[15]   = {0,0,0,1,1,1,1,1,1,2,2,2,2,2,2};
__device__ __constant__ int c_L2[15]   = {0,1,2,0,1,1,1,2,2,0,1,1,2,2,2};
__device__ __constant__ int c_L3[15]   = {0,1,2,1,0,1,2,1,2,2,1,2,0,1,2};
__device__ __constant__ int c_CGOFF[16] = {0,1,10,35,44,53,80,125,170,245,270,315,390,415,490,615};

// ---------------- CG math (verified r1) ----------------
struct cplxd { double re, im; };

__device__ inline double factd(int n) {
    double r = 1.0;
    for (int i = 2; i <= n; ++i) r *= (double)i;
    return r;
}

__device__ double cgc(int j1, int j2, int j3, int m1, int m2, int m3) {
    if (m1 + m2 != m3) return 0.0;
    double pre = sqrt((double)(2*j3+1) * factd(j3+j1-j2) * factd(j3-j1+j2) *
                      factd(j1+j2-j3) / factd(j1+j2+j3+1));
    pre *= sqrt(factd(j3+m3)*factd(j3-m3)*factd(j1-m1)*factd(j1+m1)*
                factd(j2-m2)*factd(j2+m2));
    double s = 0.0;
    for (int k = 0; k <= j1+j2-j3; ++k) {
        int d1 = j1+j2-j3-k, d2 = j1-m1-k, d3 = j2+m2-k,
            d4 = j3-j2+m1+k, d5 = j3-j1-m2+k;
        if (d1 < 0 || d2 < 0 || d3 < 0 || d4 < 0 || d5 < 0) continue;
        double term = 1.0 / (factd(k)*factd(d1)*factd(d2)*factd(d3)*factd(d4)*factd(d5));
        s += (k & 1) ? -term : term;
    }
    return pre * s;
}

__device__ inline cplxd qent(int l, int a, int i) {
    const double r2 = 0.70710678118654752440;
    double re = 0.0, im = 0.0;
    int m = a - l;
    if (m < 0) {
        if (i == l - m)      re = r2;
        else if (i == l + m) im = -r2;
    } else if (m == 0) {
        if (i == l) re = 1.0;
    } else {
        double s = (m & 1) ? -1.0 : 1.0;
        if (i == l + m)      re = s * r2;
        else if (i == l - m) im = s * r2;
    }
    if (l == 1)      { double t = re; re = im; im = -t; }  // * (-i)
    else if (l == 2) { re = -re; im = -im; }               // * (-1)
    cplxd q; q.re = re; q.im = im; return q;
}

__device__ inline float silu_f(float x) { return x / (1.0f + __expf(-x)); }

// ---------------- merged setup kernel ----------------
// block 0        : CG init
// blocks 1..8    : gate table (alpha AND 1/avg folded in)
// blocks 9..57   : node MLP
// blocks 58..    : dst histogram
__global__ __launch_bounds__(1024) void setup_kernel(
    float* __restrict__ cg_out,
    const float* __restrict__ fw1, const float* __restrict__ fb1,
    const float* __restrict__ fw2, const float* __restrict__ fb2,
    const float* __restrict__ fw3, const float* __restrict__ fb3,
    float* __restrict__ gtab,
    const int* __restrict__ A, const float* __restrict__ emb_table,
    const float* __restrict__ mw1, const float* __restrict__ mb1,
    const float* __restrict__ mw2, const float* __restrict__ mb2,
    float* __restrict__ Ai,
    const int* __restrict__ edst, int* __restrict__ cnt)
{
    const int blk = blockIdx.x;
    const int t = threadIdx.x;

    if (blk == 0) {
        __shared__ double s_re[615], s_im[615];
        __shared__ int s_flag[15];
        int p = 0;
        if (t < 615) {
            p = 14;
            while (t < c_CGOFF[p]) --p;
            int l1 = c_L1[p], l2 = c_L2[p], l3 = c_L3[p];
            int d1 = 2*l1+1, d2 = 2*l2+1, d3 = 2*l3+1;
            int local = t - c_CGOFF[p];
            int i = local / (d2*d3);
            int r = local - i*d2*d3;
            int j = r / d3;
            int k = r - j*d3;
            double accre = 0.0, accim = 0.0;
            for (int a = 0; a < d1; ++a) {
                cplxd q1 = qent(l1, a, i);
                if (q1.re == 0.0 && q1.im == 0.0) continue;
                for (int b = 0; b < d2; ++b) {
                    cplxd q2 = qent(l2, b, j);
                    if (q2.re == 0.0 && q2.im == 0.0) continue;
                    double t12r = q1.re*q2.re - q1.im*q2.im;
                    double t12i = q1.re*q2.im + q1.im*q2.re;
                    for (int c = 0; c < d3; ++c) {
                        cplxd q3 = qent(l3, c, k);
                        if (q3.re == 0.0 && q3.im == 0.0) continue;
                        int m1 = a-l1, m2 = b-l2, m3 = c-l3;
                        if (m1 + m2 != m3) continue;
                        double C = cgc(l1, l2, l3, m1, m2, m3);
                        if (C == 0.0) continue;
                        double cr = q3.re, ci = -q3.im;  // conj
                        accre += (t12r*cr - t12i*ci) * C;
                        accim += (t12r*ci + t12i*cr) * C;
                    }
                }
            }
            s_re[t] = accre; s_im[t] = accim;
        }
        __syncthreads();
        if (t < 15) {
            double sre = 0.0, sim = 0.0;
            for (int q = c_CGOFF[t]; q < c_CGOFF[t+1]; ++q) {
                sre += fabs(s_re[q]); sim += fabs(s_im[q]);
            }
            s_flag[t] = (sre >= sim) ? 0 : 1;
        }
        __syncthreads();
        if (t < 615) {
            cg_out[t] = (float)(s_flag[p] ? s_im[t] : s_re[t]);
        }
    } else if (blk <= 8) {
        const int idx = (blk - 1) * 1024 + t;
        if (idx >= TSIZE) return;
        const float len = (float)idx * (TMAX / (float)(TSIZE - 1));

        float embv[8];
#pragma unroll
        for (int b = 0; b < 8; ++b) {
            const float ctr = (2.0f/9.0f) * (float)(b+1);
            const float d = (len - ctr) * 4.5f;
            embv[b] = __expf(-d*d) * 2.5253813613805274f;  // sqrt(8)/1.12
        }
        float h1[64];
#pragma unroll
        for (int i = 0; i < 64; ++i) {
            float tt = fb1[i];
#pragma unroll
            for (int b = 0; b < 8; ++b) tt += embv[b] * fw1[b*64 + i];
            h1[i] = silu_f(tt);
        }
        float g[15];
#pragma unroll
        for (int p = 0; p < 15; ++p) g[p] = fb3[p];
        for (int j = 0; j < 64; ++j) {
            float t0 = 0.0f, t1 = 0.0f, t2 = 0.0f, t3 = 0.0f;
#pragma unroll
            for (int i = 0; i < 64; i += 4) {
                t0 += h1[i+0] * fw2[(i+0)*64 + j];
                t1 += h1[i+1] * fw2[(i+1)*64 + j];
                t2 += h1[i+2] * fw2[(i+2)*64 + j];
                t3 += h1[i+3] * fw2[(i+3)*64 + j];
            }
            const float s = silu_f(fb2[j] + ((t0 + t1) + (t2 + t3)));
#pragma unroll
            for (int p = 0; p < 15; ++p) g[p] += s * fw3[j*15 + p];
        }
        float* orow = gtab + (long long)idx * 16;
#pragma unroll
        for (int p = 0; p < 15; ++p) orow[p] = g[p] * PALPHA[p] * INV_AVG;
        orow[15] = 0.0f;
    } else if (blk <= 57) {
        const int v = (blk - 9) * 1024 + t;
        if (v >= N_NODES) return;
        int a = A[v];
        float e[16];
#pragma unroll
        for (int i = 0; i < 16; ++i) e[i] = emb_table[a*16 + i];
        float acc[8];
#pragma unroll
        for (int c = 0; c < 8; ++c) acc[c] = mb2[c];
        for (int j = 0; j < 64; ++j) {
            float tt = mb1[j];
#pragma unroll
            for (int i = 0; i < 16; ++i) tt += e[i] * mw1[i*64 + j];
            tt = silu_f(tt);
#pragma unroll
            for (int c = 0; c < 8; ++c) acc[c] += tt * mw2[j*8 + c];
        }
#pragma unroll
        for (int c = 0; c < 8; ++c) Ai[(long long)v*8 + c] = acc[c];
    } else {
        const long long idx = (long long)(blk - 58) * 1024 + t;
        if (idx < N_EDGES) atomicAdd(&cnt[edst[idx]], 1);
    }
}

// ---------------- scan: exclusive prefix of counts -> cur ----------------
__global__ __launch_bounds__(1024) void scan_kernel(const int* __restrict__ cnt,
                                                    int* __restrict__ cur) {
    __shared__ int sums[1024];
    const int t = threadIdx.x;
    const int per = 49;
    const int base = t * per;
    int s = 0;
    for (int i = 0; i < per; ++i) {
        int idx = base + i;
        if (idx < N_NODES) s += cnt[idx];
    }
    sums[t] = s;
    __syncthreads();
    for (int off = 1; off < 1024; off <<= 1) {
        int v = (t >= off) ? sums[t - off] : 0;
        __syncthreads();
        sums[t] += v;
        __syncthreads();
    }
    int run = (t == 0) ? 0 : sums[t - 1];
    for (int i = 0; i < per; ++i) {
        int idx = base + i;
        if (idx < N_NODES) {
            cur[idx] = run;
            run += cnt[idx];
        }
    }
}

// ---------------- build: geometry + scatter packed sorted records ----------------
__global__ __launch_bounds__(256) void build_kernel(
    const float* __restrict__ pos, const int* __restrict__ batch,
    const int* __restrict__ esrc, const int* __restrict__ edst,
    const float* __restrict__ eshift, const float* __restrict__ cell,
    int* __restrict__ cur,
    unsigned int* __restrict__ epair, float* __restrict__ edata)
{
    long long t = (long long)blockIdx.x * 256 + threadIdx.x;
    if (t >= N_EDGES) return;
    const int src = esrc[t];
    const int d   = edst[t];
    const int p = atomicAdd(&cur[d], 1);

    const int bb = batch[src];
    const float s0 = eshift[3*t+0], s1 = eshift[3*t+1], s2 = eshift[3*t+2];
    const float* cl = cell + (long long)bb * 9;
    const float shx = s0*cl[0] + s1*cl[3] + s2*cl[6];
    const float shy = s0*cl[1] + s1*cl[4] + s2*cl[7];
    const float shz = s0*cl[2] + s1*cl[5] + s2*cl[8];
    const float vx = pos[d*3+0] - pos[src*3+0] + shx;
    const float vy = pos[d*3+1] - pos[src*3+1] + shy;
    const float vz = pos[d*3+2] - pos[src*3+2] + shz;
    const float len = sqrtf(vx*vx + vy*vy + vz*vz);
    const float inv = 1.0f / fmaxf(len, 1e-8f);

    epair[p] = (unsigned int)src | ((unsigned int)d << 16);
    ((float4*)edata)[p] = make_float4(vx*inv, vy*inv, vz*inv, len);
}

// ---------------- per-path TP, full 16 channels (l3=0,1) ----------------
template<int P, int D3>
__device__ __attribute__((always_inline)) inline void process_path(
    float (&acc)[16*D3], const float (&Y)[9], const float (&g)[15],
    const float (&Aiv)[8], const float* __restrict__ cg, const float* __restrict__ tpw)
{
    constexpr int l1 = PL1[P], l2 = PL2[P];
    constexpr int d1 = 2*l1 + 1, d2 = 2*l2 + 1;
    constexpr int cgoff = PCGOFF[P];
    float geo[D3];
#pragma unroll
    for (int k = 0; k < D3; ++k) geo[k] = 0.0f;
#pragma unroll
    for (int m = 0; m < d1; ++m) {
#pragma unroll
        for (int n = 0; n < d2; ++n) {
            float pr = Y[l1*l1 + m] * Y[l2*l2 + n];
#pragma unroll
            for (int k = 0; k < D3; ++k)
                geo[k] += pr * cg[cgoff + (m*d2 + n)*D3 + k];
        }
    }
    float gg[D3];
#pragma unroll
    for (int k = 0; k < D3; ++k) gg[k] = geo[k] * g[P];
    float chan[16];
#pragma unroll
    for (int c = 0; c < 16; ++c) chan[c] = 0.0f;
#pragma unroll
    for (int m = 0; m < 8; ++m) {
#pragma unroll
        for (int c = 0; c < 16; ++c) chan[c] += Aiv[m] * tpw[P*128 + m*16 + c];
    }
#pragma unroll
    for (int c = 0; c < 16; ++c) {
#pragma unroll
        for (int k = 0; k < D3; ++k)
            acc[c*D3 + k] += chan[c] * gg[k];
    }
}

// ---------------- per-path TP, 8-channel half (l3=2) ----------------
template<int P, int CBASE>
__device__ __attribute__((always_inline)) inline void process_path_half(
    float (&acc)[40], const float (&Y)[9], const float (&g)[15],
    const float (&Aiv)[8], const float* __restrict__ cg, const float* __restrict__ tpw)
{
    constexpr int l1 = PL1[P], l2 = PL2[P];
    constexpr int d1 = 2*l1 + 1, d2 = 2*l2 + 1;
    constexpr int cgoff = PCGOFF[P];
    float geo[5];
#pragma unroll
    for (int k = 0; k < 5; ++k) geo[k] = 0.0f;
#pragma unroll
    for (int m = 0; m < d1; ++m) {
#pragma unroll
        for (int n = 0; n < d2; ++n) {
            float pr = Y[l1*l1 + m] * Y[l2*l2 + n];
#pragma unroll
            for (int k = 0; k < 5; ++k)
                geo[k] += pr * cg[cgoff + (m*d2 + n)*5 + k];
        }
    }
    float gg[5];
#pragma unroll
    for (int k = 0; k < 5; ++k) gg[k] = geo[k] * g[P];
    float chan[8];
#pragma unroll
    for (int c = 0; c < 8; ++c) chan[c] = 0.0f;
#pragma unroll
    for (int m = 0; m < 8; ++m) {
#pragma unroll
        for (int c = 0; c < 8; ++c) chan[c] += Aiv[m] * tpw[P*128 + m*16 + CBASE + c];
    }
#pragma unroll
    for (int c = 0; c < 8; ++c) {
#pragma unroll
        for (int k = 0; k < 5; ++k)
            acc[c*5 + k] += chan[c] * gg[k];
    }
}

// ---------------- fused edge kernel ----------------
__global__ __launch_bounds__(256) void edge_kernel(
    const unsigned int* __restrict__ epair, const float* __restrict__ edata,
    const float* __restrict__ tpw,  const float* __restrict__ cg,
    const float* __restrict__ Ai,   const float* __restrict__ gtab,
    float* __restrict__ out)
{
    __shared__ float s_stage[256*33];    // 33792 B
    __shared__ int   s_dstsh[256];
    __shared__ int   s_segstart[257];
    __shared__ int   s_segdst[256];
    __shared__ int   s_woff[5];

    const int tid  = threadIdx.x;
    const int wave = tid >> 6, lane = tid & 63;
    const long long e = (long long)blockIdx.x * 256 + tid;
    const bool act = (e < N_EDGES);
    const long long ti = act ? e : 0;

    // ---- coalesced record loads ----
    const unsigned int pk = epair[ti];
    const int src = (int)(pk & 0xffffu);
    const int mydst = act ? (int)(pk >> 16) : DSENT;
    const float4 ed = ((const float4*)edata)[ti];
    const float nx = ed.x, ny = ed.y, nz = ed.z, len = ed.w;

    float Aiv[8];
    {
        const float4* ap = (const float4*)(Ai + (long long)src * 8);
        float4 a0v = ap[0], a1v = ap[1];
        Aiv[0]=a0v.x; Aiv[1]=a0v.y; Aiv[2]=a0v.z; Aiv[3]=a0v.w;
        Aiv[4]=a1v.x; Aiv[5]=a1v.y; Aiv[6]=a1v.z; Aiv[7]=a1v.w;
    }

    // ---- segment metadata ----
    s_dstsh[tid] = mydst;
    __syncthreads();
    const int prev = (tid == 0) ? (mydst ^ 1) : s_dstsh[tid - 1];
    const int flag = (prev != mydst) ? 1 : 0;
    const unsigned long long mask = __ballot(flag != 0);
    const int excl = __popcll(mask & ((1ull << lane) - 1));
    if (lane == 0) s_woff[wave] = __popcll(mask);
    __syncthreads();
    if (tid == 0) {
        int r = 0;
#pragma unroll
        for (int w = 0; w < 4; ++w) { int c = s_woff[w]; s_woff[w] = r; r += c; }
        s_woff[4] = r;           // nseg
        s_segstart[r] = 256;     // terminator
    }
    __syncthreads();
    const int segid = s_woff[wave] + excl + flag - 1;
    if (flag) { s_segstart[segid] = tid; s_segdst[segid] = mydst; }
    __syncthreads();
    const int nseg = s_woff[4];

    // ---- per-edge math ----
    float Y[9];
    {
        const float s3c = 1.7320508075688772f;
        const float s15 = 3.872983346207417f;
        const float s5 = 2.2360679774997896f;
        Y[0] = 1.0f;
        Y[1] = s3c*ny; Y[2] = s3c*nz; Y[3] = s3c*nx;
        Y[4] = s15*nx*ny; Y[5] = s15*ny*nz;
        Y[6] = 0.5f*s5*(3.0f*nz*nz - 1.0f);
        Y[7] = s15*nx*nz;
        Y[8] = 0.5f*s15*(nx*nx - ny*ny);
    }

    float g[15];
    {
        float f = len * ((float)(TSIZE - 1) / TMAX);
        int i0 = (int)f;
        if (i0 > TSIZE - 2) i0 = TSIZE - 2;
        const float w = f - (float)i0;
        const float* t0 = gtab + (long long)i0 * 16;
        const float* t1 = t0 + 16;
#pragma unroll
        for (int p = 0; p < 15; ++p) g[p] = t0[p] + w * (t1[p] - t0[p]);
    }

#define DRAIN(BASE, NC, SH, MSK)                                             \
    {                                                                        \
        const int ntask = nseg * (NC);                                       \
        for (int task = tid; task < ntask; task += 256) {                    \
            const int seg = task >> (SH);                                    \
            const int comp = task & (MSK);                                   \
            const int s = s_segstart[seg], epos = s_segstart[seg + 1];       \
            const int d = s_segdst[seg];                                     \
            float sum = 0.0f;                                                \
            int r = s;                                                       \
            for (; r + 4 <= epos; r += 4) {                                  \
                float v0 = s_stage[(r+0)*33 + comp];                         \
                float v1 = s_stage[(r+1)*33 + comp];                         \
                float v2 = s_stage[(r+2)*33 + comp];                         \
                float v3 = s_stage[(r+3)*33 + comp];                         \
                sum += ((v0 + v1) + (v2 + v3));                              \
            }                                                                \
            for (; r < epos; ++r) sum += s_stage[r*33 + comp];               \
            if (d != DSENT)                                                  \
                atomicAdd(&out[(long long)d*144 + (BASE) + comp], sum);      \
        }                                                                    \
    }

    // ======== phase A: l3=0 (16) + l3=1 (48) ========
    {
        float a0[16], a1[48];
#pragma unroll
        for (int i = 0; i < 16; ++i) a0[i] = 0.0f;
        process_path<0, 1>(a0, Y, g, Aiv, cg, tpw);
        process_path<4, 1>(a0, Y, g, Aiv, cg, tpw);
        process_path<12,1>(a0, Y, g, Aiv, cg, tpw);
#pragma unroll
        for (int i = 0; i < 48; ++i) a1[i] = 0.0f;
        process_path<1, 3>(a1, Y, g, Aiv, cg, tpw);
        process_path<3, 3>(a1, Y, g, Aiv, cg, tpw);
        process_path<5, 3>(a1, Y, g, Aiv, cg, tpw);
        process_path<7, 3>(a1, Y, g, Aiv, cg, tpw);
        process_path<10,3>(a1, Y, g, Aiv, cg, tpw);
        process_path<13,3>(a1, Y, g, Aiv, cg, tpw);

        // PASS 0: comps 0..31 = a0[0:16] + a1[0:16]
#pragma unroll
        for (int c = 0; c < 32; ++c)
            s_stage[tid*33 + c] = (c < 16) ? a0[c] : a1[c - 16];
        __syncthreads();
        DRAIN(0, 32, 5, 31)
        __syncthreads();

        // PASS 1: comps 32..63 = a1[16:48]
#pragma unroll
        for (int c = 0; c < 32; ++c)
            s_stage[tid*33 + c] = a1[16 + c];
        __syncthreads();
        DRAIN(32, 32, 5, 31)
        __syncthreads();
    }

    // ======== phase B: l3=2, channels 0..7 ========
    float a2lo[40];
#pragma unroll
    for (int i = 0; i < 40; ++i) a2lo[i] = 0.0f;
    process_path_half<2, 0>(a2lo, Y, g, Aiv, cg, tpw);
    process_path_half<6, 0>(a2lo, Y, g, Aiv, cg, tpw);
    process_path_half<8, 0>(a2lo, Y, g, Aiv, cg, tpw);
    process_path_half<9, 0>(a2lo, Y, g, Aiv, cg, tpw);
    process_path_half<11,0>(a2lo, Y, g, Aiv, cg, tpw);
    process_path_half<14,0>(a2lo, Y, g, Aiv, cg, tpw);

    // PASS 2: comps 64..95 = a2lo[0:32]
#pragma unroll
    for (int c = 0; c < 32; ++c)
        s_stage[tid*33 + c] = a2lo[c];
    __syncthreads();
    DRAIN(64, 32, 5, 31)
    __syncthreads();

    // ======== phase C: l3=2, channels 8..15 (a2lo[32:40] still live) ========
    float a2hi[40];
#pragma unroll
    for (int i = 0; i < 40; ++i) a2hi[i] = 0.0f;
    process_path_half<2, 8>(a2hi, Y, g, Aiv, cg, tpw);
    process_path_half<6, 8>(a2hi, Y, g, Aiv, cg, tpw);
    process_path_half<8, 8>(a2hi, Y, g, Aiv, cg, tpw);
    process_path_half<9, 8>(a2hi, Y, g, Aiv, cg, tpw);
    process_path_half<11,8>(a2hi, Y, g, Aiv, cg, tpw);
    process_path_half<14,8>(a2hi, Y, g, Aiv, cg, tpw);

    // PASS 3: comps 96..127 = a2lo[32:40] + a2hi[0:24]
#pragma unroll
    for (int c = 0; c < 32; ++c)
        s_stage[tid*33 + c] = (c < 8) ? a2lo[32 + c] : a2hi[c - 8];
    __syncthreads();
    DRAIN(96, 32, 5, 31)
    __syncthreads();

    // PASS 4: comps 128..143 = a2hi[24:40]
#pragma unroll
    for (int c = 0; c < 16; ++c)
        s_stage[tid*33 + c] = a2hi[24 + c];
    __syncthreads();
    DRAIN(128, 16, 4, 15)
#undef DRAIN
}

// ---------------- launch ----------------
extern "C" void kernel_launch(void* const* d_in, const int* in_sizes, int n_in,
                              void* d_out, int out_size, void* d_ws, size_t ws_size,
                              hipStream_t stream) {
    const float* pos       = (const float*)d_in[0];
    const int*   A         = (const int*)d_in[1];
    const int*   batch     = (const int*)d_in[2];
    const int*   esrc      = (const int*)d_in[3];
    const int*   edst      = (const int*)d_in[4];
    const float* eshift    = (const float*)d_in[5];
    const float* cell      = (const float*)d_in[6];
    const float* emb_table = (const float*)d_in[7];
    const float* mlp_w1    = (const float*)d_in[8];
    const float* mlp_b1    = (const float*)d_in[9];
    const float* mlp_w2    = (const float*)d_in[10];
    const float* mlp_b2    = (const float*)d_in[11];
    const float* fc_w1     = (const float*)d_in[12];
    const float* fc_b1     = (const float*)d_in[13];
    const float* fc_w2     = (const float*)d_in[14];
    const float* fc_b2     = (const float*)d_in[15];
    const float* fc_w3     = (const float*)d_in[16];
    const float* fc_b3     = (const float*)d_in[17];
    const float* tpw       = (const float*)d_in[18];
    float* out = (float*)d_out;

    // ws layout (float offsets; all 16B-aligned)
    float*        ws_cg    = (float*)d_ws;                  // [0, 1024)
    float*        ws_Ai    = (float*)d_ws + 1024;           // 400000
    float*        ws_gtab  = (float*)d_ws + 401024;         // 131072
    int*          ws_cnt   = (int*)d_ws + 532096;           // 50016
    int*          ws_cur   = (int*)d_ws + 582112;           // 50016
    unsigned int* ws_epair = (unsigned int*)d_ws + 632128;  // 1e6
    float*        ws_edata = (float*)d_ws + 1632128;        // 4e6

    hipMemsetAsync(d_out, 0, (size_t)out_size * sizeof(float), stream);
    hipMemsetAsync(ws_cnt, 0, 50016 * sizeof(int), stream);

    // setup grid: 58 setup blocks + 977 hist blocks
    hipLaunchKernelGGL(setup_kernel, dim3(58 + 977), dim3(1024), 0, stream,
                       ws_cg,
                       fc_w1, fc_b1, fc_w2, fc_b2, fc_w3, fc_b3, ws_gtab,
                       A, emb_table, mlp_w1, mlp_b1, mlp_w2, mlp_b2, ws_Ai,
                       edst, ws_cnt);
    hipLaunchKernelGGL(scan_kernel, dim3(1), dim3(1024), 0, stream, ws_cnt, ws_cur);

    const int eblocks = (N_EDGES + 255) / 256;
    hipLaunchKernelGGL(build_kernel, dim3(eblocks), dim3(256), 0, stream,
                       pos, batch, esrc, edst, eshift, cell,
                       ws_cur, ws_epair, ws_edata);
    hipLaunchKernelGGL(edge_kernel, dim3(eblocks), dim3(256), 0, stream,
                       ws_epair, ws_edata, tpw, ws_cg, ws_Ai, ws_gtab, out);
}